// Round 11
// baseline (515.407 us; speedup 1.0000x reference)
//
#include <hip/hip_runtime.h>

typedef int      iv4 __attribute__((ext_vector_type(4)));
typedef unsigned uv4 __attribute__((ext_vector_type(4)));
typedef float    fv4 __attribute__((ext_vector_type(4)));

// ================= v11: 3-pass streaming, 2 blocks/CU on K1/K3 =============
// K1 sort16 : per-16K-chunk LDS counting sort by ptr-region -> wsp/wso/wsb
// K2 gather16: per-region LDS-staged gather (bounds in LDS) -> wsv
// K3 invert16: per-chunk LDS permutation-inversion + register run-reduction
#define NREGS2  256               // x regions, 128 KB each
#define RSH2    15                // region shift
#define REGW    (1 << RSH2)       // 32768 floats per region
#define CHUNKC  16384             // edges per chunk
#define BLKC    1024
#define EPTC    16                // CHUNKC / BLKC
#define MAXC2   2048              // max chunks (K2 LDS bounds cache)
#define SWZ(i)  ((i) ^ (((i) >> 5) & 31))   // LDS bank swizzle (involution)

// ---- K1: sort chunk by region; emit u16 sidecars (wsp: ptr, wso: orig) ----
__global__ __launch_bounds__(BLKC) void sort16_kernel(
    const int*      __restrict__ ptrs,
    unsigned short* __restrict__ wsp,  // [n_edges] region-local ptr, sorted order
    unsigned short* __restrict__ wso,  // [n_edges] original chunk pos, sorted order
    int*            __restrict__ wsb)  // [n_chunks * (NREGS2+1)] bounds
{
    __shared__ int      hist[NREGS2];
    __shared__ int      scn[NREGS2];
    __shared__ int      bounds[NREGS2 + 1];
    __shared__ unsigned packed[CHUNKC];        // 64 KB -> 2 blocks/CU

    const int c = blockIdx.x, tid = threadIdx.x;
    const long long base = (long long)c * CHUNKC;

    if (tid < NREGS2) hist[tid] = 0;
    __syncthreads();

    // coalesced ptr loads; entry orig = q*4096 + tid*4 + k
    int ps[EPTC];
    const iv4* p4 = reinterpret_cast<const iv4*>(ptrs + base);
    #pragma unroll
    for (int q = 0; q < EPTC / 4; ++q) {
        iv4 p = __builtin_nontemporal_load(p4 + q * BLKC + tid);
        ps[q*4+0] = p[0]; ps[q*4+1] = p[1]; ps[q*4+2] = p[2]; ps[q*4+3] = p[3];
    }

    #pragma unroll
    for (int i = 0; i < EPTC; ++i) atomicAdd(&hist[ps[i] >> RSH2], 1);
    __syncthreads();

    // Hillis-Steele scan over 256 counts
    if (tid < NREGS2) scn[tid] = hist[tid];
    __syncthreads();
    for (int off = 1; off < NREGS2; off <<= 1) {
        int v = 0;
        if (tid < NREGS2) { v = scn[tid]; if (tid >= off) v += scn[tid - off]; }
        __syncthreads();
        if (tid < NREGS2) scn[tid] = v;
        __syncthreads();
    }
    if (tid < NREGS2) bounds[tid + 1] = scn[tid];
    if (tid == 0) bounds[0] = 0;
    __syncthreads();
    if (tid < NREGS2) hist[tid] = bounds[tid];           // cursors
    __syncthreads();

    // rank + scatter (unstable OK: K3 inverts by orig position)
    #pragma unroll
    for (int q = 0; q < EPTC / 4; ++q) {
        #pragma unroll
        for (int k = 0; k < 4; ++k) {
            int pp   = ps[q * 4 + k];
            int orig = (q << 12) + (tid << 2) + k;       // 14 bits
            int pos  = atomicAdd(&hist[pp >> RSH2], 1);
            packed[pos] = (((unsigned)pp & (REGW - 1)) << 16) | (unsigned)orig;
        }
    }
    __syncthreads();

    // split write-out: 2 packed entries -> one u32 of ptrs + one u32 of origs
    {
        unsigned* p32 = reinterpret_cast<unsigned*>(wsp + base);
        unsigned* o32 = reinterpret_cast<unsigned*>(wso + base);
        for (int i = tid; i < CHUNKC / 2; i += BLKC) {
            unsigned a = packed[2 * i], b = packed[2 * i + 1];
            __builtin_nontemporal_store((b & 0xFFFF0000u) | (a >> 16), p32 + i);
            __builtin_nontemporal_store((b << 16) | (a & 0xFFFFu),     o32 + i);
        }
    }
    for (int i = tid; i <= NREGS2; i += BLKC)
        wsb[(size_t)c * (NREGS2 + 1) + i] = bounds[i];
}

// ---- K2: block r stages x-region r in LDS; streams all chunk slices ----
__global__ __launch_bounds__(BLKC) void gather16_kernel(
    const float*          __restrict__ x,
    const unsigned short* __restrict__ wsp,
    float*                __restrict__ wsv,
    const int*            __restrict__ wsb,
    int n_chunks, int n_x)
{
    __shared__ float xr[REGW];                 // 128 KB
    __shared__ int   blo[MAXC2];               // 8 KB
    __shared__ int   bhi[MAXC2];               // 8 KB

    const int r = blockIdx.x, tid = threadIdx.x;
    const int w = tid >> 6, lane = tid & 63;
    const long long rb = (long long)r << RSH2;

    // stage region (coalesced float4, clamped)
    {
        const fv4* xs = reinterpret_cast<const fv4*>(x + rb);
        fv4* xd = reinterpret_cast<fv4*>(xr);
        for (int i = tid; i < REGW / 4; i += BLKC)
            if (rb + (long long)(i + 1) * 4 <= n_x) xd[i] = xs[i];
    }
    // cache this region's bounds for ALL chunks
    for (int c = tid; c < n_chunks; c += BLKC) {
        blo[c] = wsb[(size_t)c * (NREGS2 + 1) + r];
        bhi[c] = wsb[(size_t)c * (NREGS2 + 1) + r + 1];
    }
    __syncthreads();

    // wave w handles chunks {w, w+16, ...}, two at a time for 2x MLP
    for (int c = w; c < n_chunks; c += 32) {
        const int c1 = c + 16;
        const int lo0 = blo[c], hi0 = bhi[c];
        const int lo1 = (c1 < n_chunks) ? blo[c1] : 0;
        const int hi1 = (c1 < n_chunks) ? bhi[c1] : 0;
        const long long cb0 = (long long)c  * CHUNKC;
        const long long cb1 = (long long)c1 * CHUNKC;
        int i0 = lo0 + lane, i1 = lo1 + lane;
        while (i0 < hi0 || i1 < hi1) {
            unsigned short a = 0, b = 0;
            const bool da = i0 < hi0, db = i1 < hi1;
            if (da) a = __builtin_nontemporal_load(wsp + cb0 + i0);
            if (db) b = __builtin_nontemporal_load(wsp + cb1 + i1);
            if (da) __builtin_nontemporal_store(xr[a], wsv + cb0 + i0);
            if (db) __builtin_nontemporal_store(xr[b], wsv + cb1 + i1);
            i0 += 64; i1 += 64;
        }
    }
}

// ---- K3: invert chunk permutation in LDS, run-reduce in original order ----
__global__ __launch_bounds__(BLKC) void invert16_kernel(
    const int*            __restrict__ csr,
    float*                __restrict__ out,
    const unsigned short* __restrict__ wso,
    const float*          __restrict__ wsv)
{
    __shared__ float vlds[CHUNKC];             // 64 KB -> 2 blocks/CU

    const int c = blockIdx.x, tid = threadIdx.x;
    const long long base = (long long)c * CHUNKC;

    // phase A: stream (orig, value); scatter value to original position
    // (permutation -> unique plain LDS writes). Fully unrolled: 6 independent
    // 16B loads in flight per thread.
    {
        const uv4* o4 = reinterpret_cast<const uv4*>(wso + base);  // 8 u16/load
        const fv4* v4 = reinterpret_cast<const fv4*>(wsv + base);
        #pragma unroll
        for (int it = 0; it < CHUNKC / (BLKC * 8); ++it) {         // 2 iters
            const int idx = it * BLKC + tid;                       // 8-entry group
            uv4 oo = __builtin_nontemporal_load(o4 + idx);
            fv4 va = __builtin_nontemporal_load(v4 + 2 * idx);
            fv4 vb = __builtin_nontemporal_load(v4 + 2 * idx + 1);
            #pragma unroll
            for (int j = 0; j < 8; ++j) {
                int   o = (int)((oo[j >> 1] >> (16 * (j & 1))) & 0xFFFFu);
                float v = (j < 4) ? va[j] : vb[j - 4];
                vlds[SWZ(o)] = v;
            }
        }
    }
    __syncthreads();

    // phase B: thread t owns edges [t*16, t*16+16) in ORIGINAL order; csr
    // sorted -> register run-accumulation; interior runs exclusive -> plain
    // store onto zeroed out; first/last run may span threads -> atomicAdd.
    {
        const int o0 = tid * EPTC;
        int cs[EPTC];
        const iv4* s4 = reinterpret_cast<const iv4*>(csr + base + o0);
        #pragma unroll
        for (int q = 0; q < EPTC / 4; ++q) {
            iv4 s = __builtin_nontemporal_load(s4 + q);
            cs[q*4+0] = s[0]; cs[q*4+1] = s[1]; cs[q*4+2] = s[2]; cs[q*4+3] = s[3];
        }
        int   cur   = cs[0];
        float sum   = 0.f;
        bool  first = true;
        #pragma unroll
        for (int i = 0; i < EPTC; ++i) {
            int seg = cs[i];
            if (seg != cur) {
                if (first) { atomicAdd(out + cur, sum); first = false; }
                else       { out[cur] = sum; }
                cur = seg;
                sum = 0.f;
            }
            sum += vlds[SWZ(o0 + i)];
        }
        atomicAdd(out + cur, sum);
    }
}

// =================== v7 fallback (proven, 128 regions) ======================
#define BLK1    512
#define EPT1    16
#define CHUNK1  (BLK1 * EPT1)
#define CPB     16
#define BLK2    1024
#define CAP     38400
#define NREGS   128
#define RSH     16

__global__ __launch_bounds__(BLK1) void sort_chunks_kernel(
    const float* __restrict__ x,
    const int*   __restrict__ ptrs,
    const int*   __restrict__ csr,
    float*       __restrict__ out,
    unsigned*    __restrict__ wse,
    int*         __restrict__ wsb,
    long long eb)
{
    __shared__ int      hist[NREGS];
    __shared__ int      bounds[NREGS + 1];
    __shared__ unsigned packed[CHUNK1];

    const int c = blockIdx.x, tid = threadIdx.x;
    const long long base = (long long)c * CHUNK1;
    const int cb = (int)(base / eb);
    const int seg_base = csr[(long long)cb * eb];

    if (tid < NREGS) hist[tid] = 0;
    __syncthreads();

    int ps[EPT1], cs[EPT1];
    const iv4* p4 = reinterpret_cast<const iv4*>(ptrs + base);
    const iv4* s4 = reinterpret_cast<const iv4*>(csr + base);
    #pragma unroll
    for (int q = 0; q < EPT1 / 4; ++q) {
        iv4 p = __builtin_nontemporal_load(p4 + q * BLK1 + tid);
        ps[q*4+0] = p[0]; ps[q*4+1] = p[1]; ps[q*4+2] = p[2]; ps[q*4+3] = p[3];
    }
    #pragma unroll
    for (int q = 0; q < EPT1 / 4; ++q) {
        iv4 s = __builtin_nontemporal_load(s4 + q * BLK1 + tid);
        cs[q*4+0] = s[0]; cs[q*4+1] = s[1]; cs[q*4+2] = s[2]; cs[q*4+3] = s[3];
    }
    #pragma unroll
    for (int i = 0; i < EPT1; ++i) atomicAdd(&hist[ps[i] >> RSH], 1);
    __syncthreads();
    if (tid == 0) {
        int acc = 0;
        #pragma unroll
        for (int r = 0; r < NREGS; ++r) { bounds[r] = acc; acc += hist[r]; }
        bounds[NREGS] = acc;
    }
    __syncthreads();
    if (tid < NREGS) hist[tid] = bounds[tid];
    __syncthreads();
    #pragma unroll
    for (int i = 0; i < EPT1; ++i) {
        int pp = ps[i], ss = cs[i];
        int r  = pp >> RSH;
        int sl = ss - seg_base;
        unsigned pk;
        if (sl >= 0xFFFF) {
            atomicAdd(out + ss, x[pp]);
            pk = (((unsigned)pp & 0xFFFFu) << 16) | 0xFFFFu;
        } else {
            pk = (((unsigned)pp & 0xFFFFu) << 16) | (unsigned)sl;
        }
        int pos = atomicAdd(&hist[r], 1);
        packed[pos] = pk;
    }
    __syncthreads();
    {
        const uv4* pl = reinterpret_cast<const uv4*>(packed);
        uv4* w4 = reinterpret_cast<uv4*>(wse + base);
        for (int i = tid; i < CHUNK1 / 4; i += BLK1)
            __builtin_nontemporal_store(pl[i], w4 + i);
    }
    for (int i = tid; i <= NREGS; i += BLK1)
        wsb[(size_t)c * (NREGS + 1) + i] = bounds[i];
}

__global__ __launch_bounds__(BLK2) void consume_kernel(
    const float*    __restrict__ x,
    const int*      __restrict__ csr,
    float*          __restrict__ out,
    const unsigned* __restrict__ wse,
    const int*      __restrict__ wsb,
    long long eb)
{
    __shared__ float accum[CAP];
    __shared__ int   cbnd[CPB][NREGS + 1];

    const int c = blockIdx.x, tid = threadIdx.x;
    const int w = tid >> 6, lane = tid & 63;
    const long long base = (long long)c * eb;

    for (int i = tid; i < CAP; i += BLK2) accum[i] = 0.f;
    {
        const int* src = wsb + (size_t)c * CPB * (NREGS + 1);
        for (int i = tid; i < CPB * (NREGS + 1); i += BLK2)
            (&cbnd[0][0])[i] = src[i];
    }
    const int seg_base = csr[base];
    const int seg_last = csr[base + eb - 1];
    __syncthreads();

    const long long chunk_base = base + (long long)w * CHUNK1;
    for (int r = 0; r < NREGS; ++r) {
        const int lo = cbnd[w][r], hi = cbnd[w][r + 1];
        const int rb = r << RSH;
        for (int i = lo + lane; i < hi; i += 64) {
            unsigned pk = __builtin_nontemporal_load(wse + chunk_base + i);
            float val = x[rb | (int)(pk >> 16)];
            int   sl  = (int)(pk & 0xFFFFu);
            if (sl == 0xFFFF) continue;
            if (sl < CAP) atomicAdd(&accum[sl], val);
            else          atomicAdd(out + seg_base + sl, val);
        }
    }
    __syncthreads();

    const int range = seg_last - seg_base + 1;
    const int hi = range < CAP ? range : CAP;
    for (int i = tid; i < hi; i += BLK2) {
        float v = accum[i];
        if (i == 0 || i == range - 1) {
            if (v != 0.f) atomicAdd(out + seg_base + i, v);
        } else {
            out[seg_base + i] = v;
        }
    }
}

// =================== round-5 fallback (generic sizes) ===================
#define EPT   16
#define BLK   256
#define CHUNK (BLK * EPT)
#define NREG  16
#define SW5(s) ((s) ^ (((s) >> 4) & 0xF))

__global__ __launch_bounds__(BLK, 4) void seg_gather_sort_kernel(
    const float* __restrict__ x,
    const int*   __restrict__ ptrs,
    const int*   __restrict__ csr,
    float*       __restrict__ out,
    int n_edges, int rshift, int n_chunks)
{
    __shared__ int      hist[NREG];
    __shared__ int      bounds[NREG + 1];
    __shared__ unsigned packed[CHUNK];
    __shared__ float    vlds[CHUNK];

    const int tid = threadIdx.x;
    const unsigned lmask = (1u << rshift) - 1u;

    for (int c = blockIdx.x; c < n_chunks; c += gridDim.x) {
        const long long base_e = (long long)c * CHUNK;
        if (base_e + CHUNK <= n_edges) {
            const long long e0 = base_e + (long long)tid * EPT;
            const iv4* p4 = reinterpret_cast<const iv4*>(ptrs + e0);
            const iv4* c4 = reinterpret_cast<const iv4*>(csr + e0);
            int ps[EPT], cs[EPT];
            #pragma unroll
            for (int q = 0; q < EPT / 4; ++q) {
                iv4 p = __builtin_nontemporal_load(p4 + q);
                ps[q*4+0] = p[0]; ps[q*4+1] = p[1]; ps[q*4+2] = p[2]; ps[q*4+3] = p[3];
            }
            #pragma unroll
            for (int q = 0; q < EPT / 4; ++q) {
                iv4 cc = __builtin_nontemporal_load(c4 + q);
                cs[q*4+0] = cc[0]; cs[q*4+1] = cc[1]; cs[q*4+2] = cc[2]; cs[q*4+3] = cc[3];
            }
            if (tid < NREG) hist[tid] = 0;
            __syncthreads();
            #pragma unroll
            for (int i = 0; i < EPT; ++i) atomicAdd(&hist[ps[i] >> rshift], 1);
            __syncthreads();
            if (tid == 0) {
                int acc = 0; bounds[0] = 0;
                #pragma unroll
                for (int r = 0; r < NREG; ++r) { acc += hist[r]; bounds[r+1] = acc; }
                #pragma unroll
                for (int r = 0; r < NREG; ++r) hist[r] = bounds[r];
            }
            __syncthreads();
            #pragma unroll
            for (int i = 0; i < EPT; ++i) {
                int r   = ps[i] >> rshift;
                int pos = atomicAdd(&hist[r], 1);
                packed[pos] = (((unsigned)ps[i] & lmask) << 12) | (unsigned)(tid*EPT+i);
            }
            __syncthreads();
            {
                int r = 0;
                #pragma unroll
                for (int k = 0; k < EPT; ++k) {
                    int e = k * BLK + tid;
                    while (e >= bounds[r + 1]) ++r;
                    unsigned pk = packed[e];
                    int ptr  = (r << rshift) | (int)(pk >> 12);
                    int slot = (int)(pk & 0xFFFu);
                    vlds[SW5(slot)] = x[ptr];
                }
            }
            __syncthreads();
            float v[EPT];
            #pragma unroll
            for (int i = 0; i < EPT; ++i) v[i] = vlds[SW5(tid * EPT + i)];
            int cur = cs[0]; float sum = 0.f; bool first = true;
            #pragma unroll
            for (int i = 0; i < EPT; ++i) {
                int seg = cs[i];
                if (seg != cur) {
                    if (first) { atomicAdd(out + cur, sum); first = false; }
                    else       { out[cur] = sum; }
                    cur = seg; sum = 0.f;
                }
                sum += v[i];
            }
            atomicAdd(out + cur, sum);
            __syncthreads();
        } else {
            long long e0 = base_e + (long long)tid * EPT;
            if (e0 < n_edges) {
                long long eend = e0 + EPT; if (eend > n_edges) eend = n_edges;
                int cur = csr[e0]; float sum = 0.f; bool first = true;
                for (long long e = e0; e < eend; ++e) {
                    int seg = csr[e];
                    if (seg != cur) {
                        if (first) { atomicAdd(out + cur, sum); first = false; }
                        else       { out[cur] = sum; }
                        cur = seg; sum = 0.f;
                    }
                    sum += x[ptrs[e]];
                }
                atomicAdd(out + cur, sum);
            }
        }
    }
}

extern "C" void kernel_launch(void* const* d_in, const int* in_sizes, int n_in,
                              void* d_out, int out_size, void* d_ws, size_t ws_size,
                              hipStream_t stream) {
    const float* x    = (const float*)d_in[0];
    const int*   ptrs = (const int*)d_in[1];
    const int*   csr  = (const int*)d_in[2];
    float*       out  = (float*)d_out;

    const int n_x     = in_sizes[0];
    const int n_edges = in_sizes[2];

    // Zero base for atomics + empty segments (d_out poisoned by harness).
    (void)hipMemsetAsync(out, 0, (size_t)out_size * sizeof(float), stream);

    // ---------------- v11 path ----------------
    const int n_chunksC = n_edges / CHUNKC;
    const size_t need11 = (size_t)n_edges * 8 +
                          (size_t)n_chunksC * (NREGS2 + 1) * 4;
    const bool ok11 = (n_edges % CHUNKC == 0) && (n_chunksC <= MAXC2) &&
                      (n_x % 4 == 0) && (n_x <= (NREGS2 << RSH2)) &&
                      (ws_size >= need11);

    // ---------------- v7 fallback ----------------
    const long long eb7 = (long long)CHUNK1 * CPB;         // 131072
    const int n_chunks1 = n_edges / CHUNK1;
    const size_t need7 = (size_t)n_edges * 4 +
                         (size_t)n_chunks1 * (NREGS + 1) * 4;
    const bool ok7 = (n_edges % eb7 == 0) && (n_x <= (NREGS << RSH)) &&
                     (ws_size >= need7);

    if (ok11) {
        // layout: [wsp u16*N][wso u16*N][wsv f32*N][wsb ints]
        unsigned short* wsp = (unsigned short*)d_ws;
        unsigned short* wso = (unsigned short*)d_ws + n_edges;
        float*          wsv = (float*)(void*)((char*)d_ws + (size_t)n_edges * 4);
        int*            wsb = (int*)(void*)((char*)d_ws + (size_t)n_edges * 8);
        sort16_kernel<<<n_chunksC, BLKC, 0, stream>>>(ptrs, wsp, wso, wsb);
        gather16_kernel<<<NREGS2, BLKC, 0, stream>>>(
            x, wsp, wsv, wsb, n_chunksC, n_x);
        invert16_kernel<<<n_chunksC, BLKC, 0, stream>>>(csr, out, wso, wsv);
    } else if (ok7) {
        unsigned* wse = (unsigned*)d_ws;
        int*      wsb = (int*)d_ws + n_edges;
        const int g2 = (int)(n_edges / eb7);
        sort_chunks_kernel<<<n_chunks1, BLK1, 0, stream>>>(
            x, ptrs, csr, out, wse, wsb, eb7);
        consume_kernel<<<g2, BLK2, 0, stream>>>(
            x, csr, out, wse, wsb, eb7);
    } else {
        int rshift = 0;
        while ((1LL << rshift) < (n_x + NREG - 1) / NREG) ++rshift;
        const int n_chunks = (int)(((long long)n_edges + CHUNK - 1) / CHUNK);
        int grid = 1024; if (grid > n_chunks) grid = n_chunks;
        seg_gather_sort_kernel<<<grid, BLK, 0, stream>>>(
            x, ptrs, csr, out, n_edges, rshift, n_chunks);
    }
}

// Round 12
// 342.086 us; speedup vs baseline: 1.5067x; 1.5067x over previous
//
#include <hip/hip_runtime.h>

typedef int      iv4 __attribute__((ext_vector_type(4)));
typedef unsigned uv4 __attribute__((ext_vector_type(4)));

// ========== v12: v7 structure + cacheable wse + 4-way region interleave =====
#define BLK1    512
#define EPT1    16
#define CHUNK1  (BLK1 * EPT1)     // 8192 edges per pass-1 chunk
#define CPB     16                // chunks per consume block (= waves in pass 2)
#define BLK2    1024
#define CAP     38400             // LDS segment-accumulator capacity (floats)
#define NREGS   128               // x regions (256 KB each at n_x = 2^23)
#define RSH     16                // region shift: ptr >> 16

// ---- Pass 1: sort each 8192-edge chunk by region, write contiguously ----
__global__ __launch_bounds__(BLK1) void sort_chunks_kernel(
    const float* __restrict__ x,     // only for the (rare) sentinel path
    const int*   __restrict__ ptrs,
    const int*   __restrict__ csr,
    float*       __restrict__ out,
    unsigned*    __restrict__ wse,   // [n_edges] packed entries, chunk-contiguous
    int*         __restrict__ wsb,   // [n_chunks * (NREGS+1)] per-chunk bounds
    long long eb)                    // edges per consume block = CPB*CHUNK1
{
    __shared__ int      hist[NREGS];      // counts -> scatter cursors
    __shared__ int      bounds[NREGS + 1];
    __shared__ unsigned packed[CHUNK1];   // 32 KB

    const int c = blockIdx.x, tid = threadIdx.x;
    const long long base = (long long)c * CHUNK1;
    const int cb = (int)(base / eb);                  // owning consume block
    const int seg_base = csr[(long long)cb * eb];

    if (tid < NREGS) hist[tid] = 0;
    __syncthreads();

    // coalesced index loads (nt: single-use stream, keep caches for wse/x)
    int ps[EPT1], cs[EPT1];
    const iv4* p4 = reinterpret_cast<const iv4*>(ptrs + base);
    const iv4* s4 = reinterpret_cast<const iv4*>(csr + base);
    #pragma unroll
    for (int q = 0; q < EPT1 / 4; ++q) {
        iv4 p = __builtin_nontemporal_load(p4 + q * BLK1 + tid);
        ps[q*4+0] = p[0]; ps[q*4+1] = p[1]; ps[q*4+2] = p[2]; ps[q*4+3] = p[3];
    }
    #pragma unroll
    for (int q = 0; q < EPT1 / 4; ++q) {
        iv4 s = __builtin_nontemporal_load(s4 + q * BLK1 + tid);
        cs[q*4+0] = s[0]; cs[q*4+1] = s[1]; cs[q*4+2] = s[2]; cs[q*4+3] = s[3];
    }

    // histogram
    #pragma unroll
    for (int i = 0; i < EPT1; ++i) atomicAdd(&hist[ps[i] >> RSH], 1);
    __syncthreads();
    if (tid == 0) {
        int acc = 0;
        #pragma unroll
        for (int r = 0; r < NREGS; ++r) { bounds[r] = acc; acc += hist[r]; }
        bounds[NREGS] = acc;                           // == CHUNK1
    }
    __syncthreads();
    if (tid < NREGS) hist[tid] = bounds[tid];          // cursors
    __syncthreads();

    // rank + scatter into LDS (unstable ranking fine: consumer accumulates
    // order-independently via LDS atomics)
    #pragma unroll
    for (int i = 0; i < EPT1; ++i) {
        int pp = ps[i], ss = cs[i];
        int r  = pp >> RSH;
        int sl = ss - seg_base;
        unsigned pk;
        if (sl >= 0xFFFF) {                            // pathological: direct add
            atomicAdd(out + ss, x[pp]);
            pk = (((unsigned)pp & 0xFFFFu) << 16) | 0xFFFFu;   // NOP sentinel
        } else {
            pk = (((unsigned)pp & 0xFFFFu) << 16) | (unsigned)sl;
        }
        int pos = atomicAdd(&hist[r], 1);
        packed[pos] = pk;
    }
    __syncthreads();

    // contiguous coalesced write-out of the sorted chunk (16 KB).
    // REGULAR stores (not nt): wse must be resident in L2/L3 so consume's
    // chain-head loads don't pay full HBM latency.
    {
        const uv4* pl = reinterpret_cast<const uv4*>(packed);
        uv4* w4 = reinterpret_cast<uv4*>(wse + base);
        for (int i = tid; i < CHUNK1 / 4; i += BLK1)
            w4[i] = pl[i];
    }
    for (int i = tid; i <= NREGS; i += BLK1)
        wsb[(size_t)c * (NREGS + 1) + i] = bounds[i];
}

// ---- Pass 2: region sweep with 4-way interleaved cursors (4x MLP) ----
__global__ __launch_bounds__(BLK2) void consume4_kernel(
    const float*    __restrict__ x,
    const int*      __restrict__ csr,
    float*          __restrict__ out,
    const unsigned* __restrict__ wse,
    const int*      __restrict__ wsb,
    long long eb)
{
    __shared__ float accum[CAP];                 // 150 KB
    __shared__ int   cbnd[CPB][NREGS + 1];       // 8.1 KB

    const int c = blockIdx.x, tid = threadIdx.x;
    const int w = tid >> 6, lane = tid & 63;
    const long long base = (long long)c * eb;

    for (int i = tid; i < CAP; i += BLK2) accum[i] = 0.f;
    {
        const int* src = wsb + (size_t)c * CPB * (NREGS + 1);
        for (int i = tid; i < CPB * (NREGS + 1); i += BLK2)
            (&cbnd[0][0])[i] = src[i];
    }
    const int seg_base = csr[base];
    const int seg_last = csr[base + eb - 1];
    __syncthreads();

    // wave w owns chunk w. Regions processed in groups of 4 with interleaved
    // cursors: 4 independent pk->x chains in flight per lane; locality window
    // is 4 x 256 KB << L2, so phase coherence across blocks is preserved.
    const unsigned* wsec = wse + base + (long long)w * CHUNK1;
    for (int g = 0; g < NREGS; g += 4) {
        const int b0 = cbnd[w][g],     b1 = cbnd[w][g + 1];
        const int b2 = cbnd[w][g + 2], b3 = cbnd[w][g + 3];
        const int b4 = cbnd[w][g + 4];
        int i0 = b0 + lane, i1 = b1 + lane, i2 = b2 + lane, i3 = b3 + lane;
        const int rb0 = (g + 0) << RSH, rb1 = (g + 1) << RSH;
        const int rb2 = (g + 2) << RSH, rb3 = (g + 3) << RSH;
        while (i0 < b1 || i1 < b2 || i2 < b3 || i3 < b4) {
            const bool d0 = i0 < b1, d1 = i1 < b2, d2 = i2 < b3, d3 = i3 < b4;
            unsigned p0 = 0, p1 = 0, p2 = 0, p3 = 0;
            if (d0) p0 = wsec[i0];
            if (d1) p1 = wsec[i1];
            if (d2) p2 = wsec[i2];
            if (d3) p3 = wsec[i3];
            float v0 = 0.f, v1 = 0.f, v2 = 0.f, v3 = 0.f;
            if (d0) v0 = x[rb0 | (int)(p0 >> 16)];
            if (d1) v1 = x[rb1 | (int)(p1 >> 16)];
            if (d2) v2 = x[rb2 | (int)(p2 >> 16)];
            if (d3) v3 = x[rb3 | (int)(p3 >> 16)];
            if (d0) {
                int sl = (int)(p0 & 0xFFFFu);
                if (sl != 0xFFFF) {
                    if (sl < CAP) atomicAdd(&accum[sl], v0);
                    else          atomicAdd(out + seg_base + sl, v0);
                }
            }
            if (d1) {
                int sl = (int)(p1 & 0xFFFFu);
                if (sl != 0xFFFF) {
                    if (sl < CAP) atomicAdd(&accum[sl], v1);
                    else          atomicAdd(out + seg_base + sl, v1);
                }
            }
            if (d2) {
                int sl = (int)(p2 & 0xFFFFu);
                if (sl != 0xFFFF) {
                    if (sl < CAP) atomicAdd(&accum[sl], v2);
                    else          atomicAdd(out + seg_base + sl, v2);
                }
            }
            if (d3) {
                int sl = (int)(p3 & 0xFFFFu);
                if (sl != 0xFFFF) {
                    if (sl < CAP) atomicAdd(&accum[sl], v3);
                    else          atomicAdd(out + seg_base + sl, v3);
                }
            }
            i0 += 64; i1 += 64; i2 += 64; i3 += 64;
        }
    }
    __syncthreads();

    // Flush: interior segments exclusive (csr sorted) -> plain coalesced
    // stores; the two block-boundary segments may be shared -> atomicAdd.
    const int range = seg_last - seg_base + 1;
    const int hi = range < CAP ? range : CAP;
    for (int i = tid; i < hi; i += BLK2) {
        float v = accum[i];
        if (i == 0 || i == range - 1) {
            if (v != 0.f) atomicAdd(out + seg_base + i, v);
        } else {
            out[seg_base + i] = v;
        }
    }
}

// =================== round-5 fallback (generic sizes) ===================
#define EPT   16
#define BLK   256
#define CHUNK (BLK * EPT)
#define NREG  16
#define SW5(s) ((s) ^ (((s) >> 4) & 0xF))

__global__ __launch_bounds__(BLK, 4) void seg_gather_sort_kernel(
    const float* __restrict__ x,
    const int*   __restrict__ ptrs,
    const int*   __restrict__ csr,
    float*       __restrict__ out,
    int n_edges, int rshift, int n_chunks)
{
    __shared__ int      hist[NREG];
    __shared__ int      bounds[NREG + 1];
    __shared__ unsigned packed[CHUNK];
    __shared__ float    vlds[CHUNK];

    const int tid = threadIdx.x;
    const unsigned lmask = (1u << rshift) - 1u;

    for (int c = blockIdx.x; c < n_chunks; c += gridDim.x) {
        const long long base_e = (long long)c * CHUNK;
        if (base_e + CHUNK <= n_edges) {
            const long long e0 = base_e + (long long)tid * EPT;
            const iv4* p4 = reinterpret_cast<const iv4*>(ptrs + e0);
            const iv4* c4 = reinterpret_cast<const iv4*>(csr + e0);
            int ps[EPT], cs[EPT];
            #pragma unroll
            for (int q = 0; q < EPT / 4; ++q) {
                iv4 p = __builtin_nontemporal_load(p4 + q);
                ps[q*4+0] = p[0]; ps[q*4+1] = p[1]; ps[q*4+2] = p[2]; ps[q*4+3] = p[3];
            }
            #pragma unroll
            for (int q = 0; q < EPT / 4; ++q) {
                iv4 cc = __builtin_nontemporal_load(c4 + q);
                cs[q*4+0] = cc[0]; cs[q*4+1] = cc[1]; cs[q*4+2] = cc[2]; cs[q*4+3] = cc[3];
            }
            if (tid < NREG) hist[tid] = 0;
            __syncthreads();
            #pragma unroll
            for (int i = 0; i < EPT; ++i) atomicAdd(&hist[ps[i] >> rshift], 1);
            __syncthreads();
            if (tid == 0) {
                int acc = 0; bounds[0] = 0;
                #pragma unroll
                for (int r = 0; r < NREG; ++r) { acc += hist[r]; bounds[r+1] = acc; }
                #pragma unroll
                for (int r = 0; r < NREG; ++r) hist[r] = bounds[r];
            }
            __syncthreads();
            #pragma unroll
            for (int i = 0; i < EPT; ++i) {
                int r   = ps[i] >> rshift;
                int pos = atomicAdd(&hist[r], 1);
                packed[pos] = (((unsigned)ps[i] & lmask) << 12) | (unsigned)(tid*EPT+i);
            }
            __syncthreads();
            {
                int r = 0;
                #pragma unroll
                for (int k = 0; k < EPT; ++k) {
                    int e = k * BLK + tid;
                    while (e >= bounds[r + 1]) ++r;
                    unsigned pk = packed[e];
                    int ptr  = (r << rshift) | (int)(pk >> 12);
                    int slot = (int)(pk & 0xFFFu);
                    vlds[SW5(slot)] = x[ptr];
                }
            }
            __syncthreads();
            float v[EPT];
            #pragma unroll
            for (int i = 0; i < EPT; ++i) v[i] = vlds[SW5(tid * EPT + i)];
            int cur = cs[0]; float sum = 0.f; bool first = true;
            #pragma unroll
            for (int i = 0; i < EPT; ++i) {
                int seg = cs[i];
                if (seg != cur) {
                    if (first) { atomicAdd(out + cur, sum); first = false; }
                    else       { out[cur] = sum; }
                    cur = seg; sum = 0.f;
                }
                sum += v[i];
            }
            atomicAdd(out + cur, sum);
            __syncthreads();
        } else {
            long long e0 = base_e + (long long)tid * EPT;
            if (e0 < n_edges) {
                long long eend = e0 + EPT; if (eend > n_edges) eend = n_edges;
                int cur = csr[e0]; float sum = 0.f; bool first = true;
                for (long long e = e0; e < eend; ++e) {
                    int seg = csr[e];
                    if (seg != cur) {
                        if (first) { atomicAdd(out + cur, sum); first = false; }
                        else       { out[cur] = sum; }
                        cur = seg; sum = 0.f;
                    }
                    sum += x[ptrs[e]];
                }
                atomicAdd(out + cur, sum);
            }
        }
    }
}

extern "C" void kernel_launch(void* const* d_in, const int* in_sizes, int n_in,
                              void* d_out, int out_size, void* d_ws, size_t ws_size,
                              hipStream_t stream) {
    const float* x    = (const float*)d_in[0];
    const int*   ptrs = (const int*)d_in[1];
    const int*   csr  = (const int*)d_in[2];
    float*       out  = (float*)d_out;

    const int n_x     = in_sizes[0];
    const int n_edges = in_sizes[2];

    // Zero base for atomics + empty segments (d_out poisoned by harness).
    (void)hipMemsetAsync(out, 0, (size_t)out_size * sizeof(float), stream);

    const long long eb = (long long)CHUNK1 * CPB;     // 131072
    const int n_chunks1 = n_edges / CHUNK1;
    const size_t ws_need = (size_t)n_edges * 4 +
                           (size_t)n_chunks1 * (NREGS + 1) * 4;
    const bool v12_ok = (n_edges % eb == 0) &&
                        (n_x <= (NREGS << RSH)) &&
                        (ws_size >= ws_need);

    if (v12_ok) {
        unsigned* wse = (unsigned*)d_ws;
        int*      wsb = (int*)d_ws + n_edges;
        const int g2  = (int)(n_edges / eb);          // 256 consume blocks
        sort_chunks_kernel<<<n_chunks1, BLK1, 0, stream>>>(
            x, ptrs, csr, out, wse, wsb, eb);
        consume4_kernel<<<g2, BLK2, 0, stream>>>(
            x, csr, out, wse, wsb, eb);
    } else {
        int rshift = 0;
        while ((1LL << rshift) < (n_x + NREG - 1) / NREG) ++rshift;
        const int n_chunks = (int)(((long long)n_edges + CHUNK - 1) / CHUNK);
        int grid = 1024; if (grid > n_chunks) grid = n_chunks;
        seg_gather_sort_kernel<<<grid, BLK, 0, stream>>>(
            x, ptrs, csr, out, n_edges, rshift, n_chunks);
    }
}